// Round 1
// baseline (78.103 us; speedup 1.0000x reference)
//
#include <hip/hip_runtime.h>
#include <math.h>

static constexpr int H = 512, W = 512, NPTS = 19, BATCH = 4;
static constexpr int HW = H * W;
static constexpr int NPLANES = BATCH * NPTS;                 // 76
static constexpr long long TOTAL = (long long)NPLANES * HW;  // 19,922,944 (per channel group)
static constexpr float INV_OFF = 1.0f / 40.0f;

// Main pass: grid = (blocksX, 76). Each (b,n) plane streamed by blocksX*256
// threads with float4 loads from the three channel groups (heat logits,
// offset-x preds, offset-y preds). Targets are computed analytically from the
// landmark — no map materialization, no gather.
__global__ __launch_bounds__(256) void homl_main(
    const float* __restrict__ fm, const int* __restrict__ lm,
    double* __restrict__ partials, int blocksX)
{
    const int bn = blockIdx.y;             // 0..75
    const int b  = bn / NPTS;
    const int n  = bn % NPTS;

    int x = lm[bn * 2 + 0];
    int y = lm[bn * 2 + 1];
    x = min(max(x, 1), W - 1);             // clamp_landmarks
    y = min(max(y, 1), H - 1);

    const float* ph_base = fm + ((size_t)b * 3 * NPTS + n) * HW;
    const float* px_base = ph_base + (size_t)NPTS * HW;
    const float* py_base = px_base + (size_t)NPTS * HW;

    float bce = 0.0f, lxs = 0.0f, lys = 0.0f;
    int cnt = 0;

    const int nvec = HW / 4;               // 65536 float4 per plane
    for (int v = blockIdx.x * blockDim.x + threadIdx.x; v < nvec;
         v += blocksX * blockDim.x) {
        const int p = v * 4;
        const int i = p >> 9;              // row (W = 512)
        const int j = p & (W - 1);         // col of first of 4

        float phv[4], pxv[4], pyv[4];
        *reinterpret_cast<float4*>(phv) = *reinterpret_cast<const float4*>(ph_base + p);
        *reinterpret_cast<float4*>(pxv) = *reinterpret_cast<const float4*>(px_base + p);
        *reinterpret_cast<float4*>(pyv) = *reinterpret_cast<const float4*>(py_base + p);

        const int   dy  = i - y;
        const int   dy2 = dy * dy;
        const float tx  = (float)(y - i) * INV_OFF;   // offmap_x target (same for all 4)

        #pragma unroll
        for (int k = 0; k < 4; ++k) {
            const int dx = j + k - x;
            const int d2 = dy2 + dx * dx;
            const float ph = phv[k];
            // stable BCE-with-logits: max(ph,0) - ph*th + log1p(exp(-|ph|))
            bce += fmaxf(ph, 0.0f) + log1pf(expf(-fabsf(ph)));
            if (d2 <= 1600) {              // th == 1, ind == 1
                bce -= ph;
                cnt += 1;
                lxs += fabsf(pxv[k] - tx);
                lys += fabsf(pyv[k] - (float)(x - (j + k)) * INV_OFF);
            }
        }
    }

    // wave (64-lane) reduction
    #pragma unroll
    for (int off = 32; off > 0; off >>= 1) {
        bce += __shfl_down(bce, off);
        lxs += __shfl_down(lxs, off);
        lys += __shfl_down(lys, off);
        cnt += __shfl_down(cnt, off);
    }

    __shared__ float redf[3][4];
    __shared__ int   redc[4];
    const int wave = threadIdx.x >> 6;
    const int lane = threadIdx.x & 63;
    if (lane == 0) {
        redf[0][wave] = bce; redf[1][wave] = lxs; redf[2][wave] = lys;
        redc[wave] = cnt;
    }
    __syncthreads();
    if (threadIdx.x == 0) {
        double db = 0.0, dxs = 0.0, dys = 0.0; long long dc = 0;
        #pragma unroll
        for (int wv = 0; wv < 4; ++wv) {
            db += (double)redf[0][wv];
            dxs += (double)redf[1][wv];
            dys += (double)redf[2][wv];
            dc += redc[wv];
        }
        const int slot = blockIdx.y * blocksX + blockIdx.x;
        double4 o; o.x = db; o.y = dxs; o.z = dys; o.w = (double)dc;
        *reinterpret_cast<double4*>(partials + (size_t)slot * 4) = o;
    }
}

__global__ __launch_bounds__(256) void homl_final(
    const double* __restrict__ partials, int nslots, float* __restrict__ out)
{
    double b = 0.0, xs = 0.0, ys = 0.0, c = 0.0;
    for (int s = threadIdx.x; s < nslots; s += 256) {
        b  += partials[(size_t)s * 4 + 0];
        xs += partials[(size_t)s * 4 + 1];
        ys += partials[(size_t)s * 4 + 2];
        c  += partials[(size_t)s * 4 + 3];
    }
    #pragma unroll
    for (int off = 32; off > 0; off >>= 1) {
        b  += __shfl_down(b, off);
        xs += __shfl_down(xs, off);
        ys += __shfl_down(ys, off);
        c  += __shfl_down(c, off);
    }
    __shared__ double sd[4][4];
    const int wave = threadIdx.x >> 6;
    const int lane = threadIdx.x & 63;
    if (lane == 0) { sd[0][wave] = b; sd[1][wave] = xs; sd[2][wave] = ys; sd[3][wave] = c; }
    __syncthreads();
    if (threadIdx.x == 0) {
        double tb = 0.0, txs = 0.0, tys = 0.0, tc = 0.0;
        #pragma unroll
        for (int wv = 0; wv < 4; ++wv) {
            tb += sd[0][wv]; txs += sd[1][wv]; tys += sd[2][wv]; tc += sd[3][wv];
        }
        const double bce_mean = tb / (double)TOTAL;
        out[0] = (float)(2.0 * bce_mean + txs / tc + tys / tc);
    }
}

extern "C" void kernel_launch(void* const* d_in, const int* in_sizes, int n_in,
                              void* d_out, int out_size, void* d_ws, size_t ws_size,
                              hipStream_t stream) {
    const float* fm  = (const float*)d_in[0];
    const int*   lm  = (const int*)d_in[1];
    float*       out = (float*)d_out;
    double*      ws  = (double*)d_ws;

    int blocksX = 32;                                   // 32*76 = 2432 blocks (~9.5/CU)
    size_t need = (size_t)blocksX * NPLANES * 4 * sizeof(double);
    if (need > ws_size) {
        blocksX = (int)(ws_size / ((size_t)NPLANES * 4 * sizeof(double)));
        if (blocksX < 1) blocksX = 1;
    }
    const int nslots = blocksX * NPLANES;

    dim3 grid(blocksX, NPLANES);
    homl_main<<<grid, 256, 0, stream>>>(fm, lm, ws, blocksX);
    homl_final<<<1, 256, 0, stream>>>(ws, nslots, out);
}

// Round 3
// 45.030 us; speedup vs baseline: 1.7345x; 1.7345x over previous
//
#include <hip/hip_runtime.h>
#include <math.h>

static constexpr int H = 512, W = 512, NPTS = 19, BATCH = 4;
static constexpr int HW = H * W;
static constexpr int NPLANES = BATCH * NPTS;                 // 76
static constexpr long long TOTAL = (long long)NPLANES * HW;  // 19,922,944 per channel group
static constexpr float INV_OFF = 1.0f / 40.0f;

static constexpr int BLOCKSX = 16;                 // 16*76 = 1216 blocks = 4864 waves (all resident)
static constexpr int NVEC = HW / 4;                // 65536 float4 per plane
static constexpr int SITER = NVEC / (BLOCKSX * 256);  // 16 steps/thread, compile-time

// Each (b,n) plane: BLOCKSX blocks, each owning a contiguous chunk of
// SITER*256 float4s per stream. Register double-buffer: loads for step s+1
// are issued before computing step s, so 3 dwordx4 stay in flight under the
// transcendental work. Targets computed analytically from the landmark.
__global__ __launch_bounds__(256) void homl_main(
    const float* __restrict__ fm, const int* __restrict__ lm,
    double* __restrict__ partials)
{
    const int bn = blockIdx.y;             // 0..75
    const int b  = bn / NPTS;
    const int n  = bn % NPTS;

    int x = lm[bn * 2 + 0];
    int y = lm[bn * 2 + 1];
    x = min(max(x, 1), W - 1);             // clamp_landmarks
    y = min(max(y, 1), H - 1);

    const float* ph_base = fm + ((size_t)b * 3 * NPTS + n) * HW;
    const float* px_base = ph_base + (size_t)NPTS * HW;
    const float* py_base = px_base + (size_t)NPTS * HW;

    const int v0 = blockIdx.x * (SITER * 256) + threadIdx.x;   // vec index, step stride 256

    float bce = 0.0f, lxs = 0.0f, lys = 0.0f, cntf = 0.0f;

    float4 bufA[2], bufB[2], bufC[2];
    {
        const int p = v0 * 4;
        bufA[0] = *reinterpret_cast<const float4*>(ph_base + p);
        bufB[0] = *reinterpret_cast<const float4*>(px_base + p);
        bufC[0] = *reinterpret_cast<const float4*>(py_base + p);
    }

    #pragma unroll
    for (int s = 0; s < SITER; ++s) {
        const int cur = s & 1, nxt = cur ^ 1;      // compile-time under full unroll
        if (s + 1 < SITER) {
            const int p = (v0 + (s + 1) * 256) * 4;
            bufA[nxt] = *reinterpret_cast<const float4*>(ph_base + p);
            bufB[nxt] = *reinterpret_cast<const float4*>(px_base + p);
            bufC[nxt] = *reinterpret_cast<const float4*>(py_base + p);
        }

        const int p   = (v0 + s * 256) * 4;
        const int i   = p >> 9;                    // row (W = 512)
        const int j   = p & (W - 1);               // col of first of 4
        const int dy  = i - y;
        const int dy2 = dy * dy;
        const float tx = (float)(y - i) * INV_OFF; // offmap_x target (same for all 4)

        const float pha[4] = {bufA[cur].x, bufA[cur].y, bufA[cur].z, bufA[cur].w};
        const float pxa[4] = {bufB[cur].x, bufB[cur].y, bufB[cur].z, bufB[cur].w};
        const float pya[4] = {bufC[cur].x, bufC[cur].y, bufC[cur].z, bufC[cur].w};

        #pragma unroll
        for (int k = 0; k < 4; ++k) {
            const int dx = j + k - x;
            const int d2 = dy2 + dx * dx;
            const float ph = pha[k];
            // stable BCE-with-logits via native exp2/log2:
            // max(ph,0) - ph*th + ln2 * log2(1 + 2^(-|ph|*log2e))
            const float a  = fabsf(ph);
            const float sp = 0.69314718056f *
                             log2f(1.0f + exp2f(-1.44269504089f * a));
            bce += fmaxf(ph, 0.0f) + sp;

            const bool in = (d2 <= 1600);          // th == 1, ind == 1
            bce  -= in ? ph : 0.0f;
            cntf += in ? 1.0f : 0.0f;
            const float ty = (float)(x - (j + k)) * INV_OFF;
            lxs += in ? fabsf(pxa[k] - tx) : 0.0f;
            lys += in ? fabsf(pya[k] - ty) : 0.0f;
        }
    }

    // wave (64-lane) reduction
    #pragma unroll
    for (int off = 32; off > 0; off >>= 1) {
        bce  += __shfl_down(bce, off);
        lxs  += __shfl_down(lxs, off);
        lys  += __shfl_down(lys, off);
        cntf += __shfl_down(cntf, off);
    }

    __shared__ float redf[4][4];
    const int wave = threadIdx.x >> 6;
    const int lane = threadIdx.x & 63;
    if (lane == 0) {
        redf[0][wave] = bce; redf[1][wave] = lxs;
        redf[2][wave] = lys; redf[3][wave] = cntf;
    }
    __syncthreads();
    if (threadIdx.x == 0) {
        double db = 0.0, dxs = 0.0, dys = 0.0, dc = 0.0;
        #pragma unroll
        for (int wv = 0; wv < 4; ++wv) {
            db  += (double)redf[0][wv];
            dxs += (double)redf[1][wv];
            dys += (double)redf[2][wv];
            dc  += (double)redf[3][wv];
        }
        const int slot = blockIdx.y * BLOCKSX + blockIdx.x;
        double4 o; o.x = db; o.y = dxs; o.z = dys; o.w = dc;
        *reinterpret_cast<double4*>(partials + (size_t)slot * 4) = o;
    }
}

__global__ __launch_bounds__(256) void homl_final(
    const double* __restrict__ partials, int nslots, float* __restrict__ out)
{
    double b = 0.0, xs = 0.0, ys = 0.0, c = 0.0;
    for (int s = threadIdx.x; s < nslots; s += 256) {
        b  += partials[(size_t)s * 4 + 0];
        xs += partials[(size_t)s * 4 + 1];
        ys += partials[(size_t)s * 4 + 2];
        c  += partials[(size_t)s * 4 + 3];
    }
    #pragma unroll
    for (int off = 32; off > 0; off >>= 1) {
        b  += __shfl_down(b, off);
        xs += __shfl_down(xs, off);
        ys += __shfl_down(ys, off);
        c  += __shfl_down(c, off);
    }
    __shared__ double sd[4][4];
    const int wave = threadIdx.x >> 6;
    const int lane = threadIdx.x & 63;
    if (lane == 0) { sd[0][wave] = b; sd[1][wave] = xs; sd[2][wave] = ys; sd[3][wave] = c; }
    __syncthreads();
    if (threadIdx.x == 0) {
        double tb = 0.0, txs = 0.0, tys = 0.0, tc = 0.0;
        #pragma unroll
        for (int wv = 0; wv < 4; ++wv) {
            tb += sd[0][wv]; txs += sd[1][wv]; tys += sd[2][wv]; tc += sd[3][wv];
        }
        const double bce_mean = tb / (double)TOTAL;
        out[0] = (float)(2.0 * bce_mean + txs / tc + tys / tc);
    }
}

extern "C" void kernel_launch(void* const* d_in, const int* in_sizes, int n_in,
                              void* d_out, int out_size, void* d_ws, size_t ws_size,
                              hipStream_t stream) {
    const float* fm  = (const float*)d_in[0];
    const int*   lm  = (const int*)d_in[1];
    float*       out = (float*)d_out;
    double*      ws  = (double*)d_ws;

    const int nslots = BLOCKSX * NPLANES;      // 1216 slots * 32 B = 39 KB scratch
    dim3 grid(BLOCKSX, NPLANES);
    homl_main<<<grid, 256, 0, stream>>>(fm, lm, ws);
    homl_final<<<1, 256, 0, stream>>>(ws, nslots, out);
}